// Round 1
// baseline (233.452 us; speedup 1.0000x reference)
//
#include <hip/hip_runtime.h>

// ---------------------------------------------------------------------------
// AttentionPairBias on MI355X (gfx950).
// Pipeline (all fp16-MFMA GEMMs accumulate in fp32; LN/softmax/sigmoid fp32):
//   1. convert s, k_in  fp32 -> fp16
//   2. transpose-convert wq,wk,wv,wg,wo fp32(K,N) -> fp16(N,K)   (so MFMA B-frag
//      reads are contiguous 16B LDS chunks, same as A)
//   3. ln_bias: one pass over z (268 MB): LayerNorm + (.)@wz fused via
//      bias = rsig*(dot(z,gw)-mu*G) + bw  -> attn buffer (B,H,N,N) fp32
//   4. gemm_fused grid(64,4): q=s@wq+bq, k=kin@wk, v=kin@wv, g=sigmoid(s@wg)
//   5. transpose v -> vT (B,H,D,N) for PV B-frags
//   6. logits: attn = QK^T/8 + attn(bias) + (1-mask)*(-1e6)   (MFMA, RMW)
//   7. softmax per row (wave/row), writes fp16 P aliased over logits rows
//   8. pv: o = P@V (MFMA)
//   9. x = fp16(g*o)
//  10. gemm_fused grid(64,1) mode 4: out = x@wo  (fp32 to d_out)
// ---------------------------------------------------------------------------

typedef _Float16 h8 __attribute__((ext_vector_type(8)));
typedef _Float16 h4 __attribute__((ext_vector_type(4)));
typedef float f32x4 __attribute__((ext_vector_type(4)));

#define MFMA16(a, b, c) __builtin_amdgcn_mfma_f32_16x16x32_f16(a, b, c, 0, 0, 0)

// workspace layout (bytes), total 64 MiB
static constexpr size_t OFF_S16   = 0;          // 1M fp16
static constexpr size_t OFF_KIN16 = 2097152;
static constexpr size_t OFF_WQT   = 4194304;
static constexpr size_t OFF_WKT   = 6291456;
static constexpr size_t OFF_WVT   = 8388608;
static constexpr size_t OFF_WGT   = 10485760;
static constexpr size_t OFF_WOT   = 12582912;
static constexpr size_t OFF_Q16   = 14680064;
static constexpr size_t OFF_K16   = 16777216;
static constexpr size_t OFF_V16   = 18874368;
static constexpr size_t OFF_VT16  = 20971520;
static constexpr size_t OFF_X16   = 23068672;
static constexpr size_t OFF_G32   = 25165824;   // 1M fp32
static constexpr size_t OFF_O32   = 29360128;   // 1M fp32
static constexpr size_t OFF_ATTN  = 33554432;   // 2*16*512*512 fp32 = 32 MiB

// --------------------------- fp32 -> fp16 convert ---------------------------
__global__ __launch_bounds__(256) void conv_f16_kernel(
    const float* __restrict__ in, _Float16* __restrict__ out, int n8) {
  int i = blockIdx.x * 256 + threadIdx.x;
  if (i >= n8) return;
  const float4* p = (const float4*)in + (size_t)i * 2;
  float4 a = p[0], b = p[1];
  h8 v;
  v[0] = (_Float16)a.x; v[1] = (_Float16)a.y; v[2] = (_Float16)a.z; v[3] = (_Float16)a.w;
  v[4] = (_Float16)b.x; v[5] = (_Float16)b.y; v[6] = (_Float16)b.z; v[7] = (_Float16)b.w;
  *(h8*)(out + (size_t)i * 8) = v;
}

// ------------------- transpose-convert weights (K,N)->(N,K) -----------------
__global__ __launch_bounds__(256) void convT_f16_kernel(
    const float* __restrict__ w0, const float* __restrict__ w1,
    const float* __restrict__ w2, const float* __restrict__ w3,
    const float* __restrict__ w4,
    _Float16* __restrict__ o0, _Float16* __restrict__ o1,
    _Float16* __restrict__ o2, _Float16* __restrict__ o3,
    _Float16* __restrict__ o4) {
  const float* w; _Float16* o;
  switch (blockIdx.y) {
    case 0: w = w0; o = o0; break;
    case 1: w = w1; o = o1; break;
    case 2: w = w2; o = o2; break;
    case 3: w = w3; o = o3; break;
    default: w = w4; o = o4; break;
  }
  int tile = blockIdx.x, tr = tile >> 4, tc = tile & 15;  // 16x16 tiles of 64
  __shared__ _Float16 ts[64][72];
  int t = threadIdx.x;
#pragma unroll
  for (int p = 0; p < 4; ++p) {
    int e = p * 1024 + t * 4;
    int r = e >> 6, c = e & 63;
    float4 v = *(const float4*)(w + (size_t)(tr * 64 + r) * 1024 + tc * 64 + c);
    h4 hv;
    hv[0] = (_Float16)v.x; hv[1] = (_Float16)v.y; hv[2] = (_Float16)v.z; hv[3] = (_Float16)v.w;
    *(h4*)&ts[r][c] = hv;
  }
  __syncthreads();
#pragma unroll
  for (int p = 0; p < 4; ++p) {
    int e = p * 1024 + t * 4;
    int n = e >> 6, k = e & 63;
    h4 hv;
#pragma unroll
    for (int u = 0; u < 4; ++u) hv[u] = ts[k + u][n];
    *(h4*)(o + (size_t)(tc * 64 + n) * 1024 + tr * 64 + k) = hv;
  }
}

// --------------------- LayerNorm(z) @ wz  ->  bias buffer -------------------
// bias[b,h,i,j] = rsig_ij*(dot(z_ij, gw[:,h]) - mu_ij*G[h]) + bw[h]
//   gw[c][h] = ln_g[c]*wz[c][h], G[h] = sum_c gw, bw[h] = sum_c ln_b[c]*wz[c][h]
__global__ __launch_bounds__(256) void ln_bias_kernel(
    const float* __restrict__ z, const float* __restrict__ ln_g,
    const float* __restrict__ ln_b, const float* __restrict__ wz,
    float* __restrict__ attn) {
  int jc = blockIdx.x, i = blockIdx.y, b = blockIdx.z;
  __shared__ float zs[64][132];   // pad 132: fp32x4-aligned, conflict-free reads
  __shared__ float gw[128][16];
  __shared__ float mu_s[64], rs_s[64], bw_s[16], G_s[16];
  __shared__ float outs[64][17];
  int t = threadIdx.x;
  for (int e = t; e < 2048; e += 256) {
    int c = e >> 4, h = e & 15;
    gw[c][h] = ln_g[c] * wz[e];
  }
  if (t < 32) {
    int h = t & 15; bool isG = t >= 16;
    float s = 0.f;
    for (int c = 0; c < 128; ++c) s += (isG ? ln_g[c] : ln_b[c]) * wz[c * 16 + h];
    if (isG) G_s[h] = s; else bw_s[h] = s;
  }
  const float* zb = z + (((size_t)b * 512 + i) * 512 + (size_t)jc * 64) * 128;
#pragma unroll
  for (int p = 0; p < 8; ++p) {
    int e = p * 1024 + t * 4;
    int r = e >> 7, c = e & 127;
    *(float4*)&zs[r][c] = *(const float4*)(zb + (size_t)r * 128 + c);
  }
  __syncthreads();
  {  // per-row mean/var: 4 threads per row, strided columns
    int jj = t >> 2, q = t & 3;
    float s1 = 0.f, s2 = 0.f;
    for (int cc = 0; cc < 32; ++cc) {
      float v = zs[jj][q + cc * 4];
      s1 += v; s2 += v * v;
    }
    s1 += __shfl_xor(s1, 1, 64); s2 += __shfl_xor(s2, 1, 64);
    s1 += __shfl_xor(s1, 2, 64); s2 += __shfl_xor(s2, 2, 64);
    if (q == 0) {
      float mu = s1 * (1.0f / 128.0f);
      float var = s2 * (1.0f / 128.0f) - mu * mu;
      mu_s[jj] = mu;
      rs_s[jj] = rsqrtf(var + 1e-5f);
    }
  }
  __syncthreads();
  {  // thread: one row (jj), 4 heads
    int jj = t >> 2, hg = (t & 3) * 4;
    float acc0 = 0.f, acc1 = 0.f, acc2 = 0.f, acc3 = 0.f;
    for (int c = 0; c < 128; ++c) {
      float zv = zs[jj][c];
      acc0 += zv * gw[c][hg + 0];
      acc1 += zv * gw[c][hg + 1];
      acc2 += zv * gw[c][hg + 2];
      acc3 += zv * gw[c][hg + 3];
    }
    float mu = mu_s[jj], rs = rs_s[jj];
    outs[jj][hg + 0] = rs * (acc0 - mu * G_s[hg + 0]) + bw_s[hg + 0];
    outs[jj][hg + 1] = rs * (acc1 - mu * G_s[hg + 1]) + bw_s[hg + 1];
    outs[jj][hg + 2] = rs * (acc2 - mu * G_s[hg + 2]) + bw_s[hg + 2];
    outs[jj][hg + 3] = rs * (acc3 - mu * G_s[hg + 3]) + bw_s[hg + 3];
  }
  __syncthreads();
  for (int e = t; e < 1024; e += 256) {  // coalesced plane writes
    int h2 = e >> 6, jj2 = e & 63;
    attn[(((size_t)(b * 16 + h2) * 512) + i) * 512 + (size_t)jc * 64 + jj2] = outs[jj2][h2];
  }
}

// ------------------------ fused 1024^3 GEMMs (MFMA fp16) --------------------
// mode 0: q=s@wqT^T+bq  1: k=kin@wk  2: v=kin@wv  3: g=sigmoid(s@wg)  4: out=x@wo
__global__ __launch_bounds__(256) void gemm_fused(
    const _Float16* __restrict__ s16, const _Float16* __restrict__ kin16,
    const _Float16* __restrict__ x16,
    const _Float16* __restrict__ wqT, const _Float16* __restrict__ wkT,
    const _Float16* __restrict__ wvT, const _Float16* __restrict__ wgT,
    const _Float16* __restrict__ woT, const float* __restrict__ bq,
    _Float16* __restrict__ q16, _Float16* __restrict__ k16,
    _Float16* __restrict__ v16, float* __restrict__ g32,
    float* __restrict__ out32, int mode_base) {
  int mode = mode_base + blockIdx.y;
  const _Float16 *A, *BT;
  switch (mode) {
    case 0: A = s16;   BT = wqT; break;
    case 1: A = kin16; BT = wkT; break;
    case 2: A = kin16; BT = wvT; break;
    case 3: A = s16;   BT = wgT; break;
    default: A = x16;  BT = woT; break;
  }
  int tile = blockIdx.x, bm = tile >> 3, bn = tile & 7;
  __shared__ _Float16 As[128][40];
  __shared__ _Float16 Bs[128][40];
  int t = threadIdx.x, wid = t >> 6, lane = t & 63;
  int wr = wid >> 1, wc = wid & 1;
  int lr = lane & 15, hi = lane >> 4;
  f32x4 acc[4][4] = {};
  for (int kt = 0; kt < 32; ++kt) {
    int k0 = kt * 32;
#pragma unroll
    for (int p = 0; p < 2; ++p) {
      int idx = p * 256 + t;
      int r = idx >> 2, c = (idx & 3) << 3;
      int4 da = *(const int4*)(A + (size_t)(bm * 128 + r) * 1024 + k0 + c);
      int4 db = *(const int4*)(BT + (size_t)(bn * 128 + r) * 1024 + k0 + c);
      *(int4*)&As[r][c] = da;
      *(int4*)&Bs[r][c] = db;
    }
    __syncthreads();
    h8 af[4], bf[4];
#pragma unroll
    for (int mi = 0; mi < 4; ++mi) af[mi] = *(const h8*)&As[wr * 64 + mi * 16 + lr][hi * 8];
#pragma unroll
    for (int ni = 0; ni < 4; ++ni) bf[ni] = *(const h8*)&Bs[wc * 64 + ni * 16 + lr][hi * 8];
#pragma unroll
    for (int mi = 0; mi < 4; ++mi)
#pragma unroll
      for (int ni = 0; ni < 4; ++ni)
        acc[mi][ni] = MFMA16(af[mi], bf[ni], acc[mi][ni]);
    __syncthreads();
  }
#pragma unroll
  for (int mi = 0; mi < 4; ++mi)
#pragma unroll
    for (int ni = 0; ni < 4; ++ni)
#pragma unroll
      for (int r = 0; r < 4; ++r) {
        int row = bm * 128 + wr * 64 + mi * 16 + hi * 4 + r;
        int col = bn * 128 + wc * 64 + ni * 16 + lr;
        float v = acc[mi][ni][r];
        size_t o = (size_t)row * 1024 + col;
        switch (mode) {
          case 0: q16[o] = (_Float16)(v + bq[col]); break;
          case 1: k16[o] = (_Float16)v; break;
          case 2: v16[o] = (_Float16)v; break;
          case 3: g32[o] = 1.0f / (1.0f + __expf(-v)); break;
          default: out32[o] = v; break;
        }
      }
}

// --------------------------- v (B,N,H,D) -> vT (B,H,D,N) --------------------
__global__ __launch_bounds__(256) void transpose_v_kernel(
    const _Float16* __restrict__ v16, _Float16* __restrict__ vT) {
  int gid = blockIdx.x * 256 + threadIdx.x;  // 131072 total
  int bh = gid >> 12;
  int rem = gid & 4095;
  int d = rem >> 6;
  int j0 = (rem & 63) << 3;
  int b = bh >> 4, h = bh & 15;
  const _Float16* src = v16 + ((size_t)b * 512) * 1024 + h * 64 + d;
  h8 vv;
#pragma unroll
  for (int u = 0; u < 8; ++u) vv[u] = src[(size_t)(j0 + u) * 1024];
  *(h8*)(vT + ((size_t)bh * 64 + d) * 512 + j0) = vv;
}

// --------------------- logits = QK^T/8 + bias + mask (MFMA) -----------------
__global__ __launch_bounds__(256) void logits_kernel(
    const _Float16* __restrict__ q16, const _Float16* __restrict__ k16,
    float* __restrict__ attn, const float* __restrict__ mask) {
  int bh = blockIdx.y, b = bh >> 4, h = bh & 15;
  int tile = blockIdx.x, ti = tile >> 2, tj = tile & 3;
  __shared__ _Float16 Qs[128][72];
  __shared__ _Float16 Ks[128][72];
  int t = threadIdx.x, wid = t >> 6, lane = t & 63;
  int wr = wid >> 1, wc = wid & 1, lr = lane & 15, hi = lane >> 4;
  const _Float16* qb = q16 + ((size_t)b * 512) * 1024 + h * 64;
  const _Float16* kb = k16 + ((size_t)b * 512) * 1024 + h * 64;
#pragma unroll
  for (int p = 0; p < 4; ++p) {
    int idx = p * 256 + t;
    int r = idx >> 3, c = (idx & 7) << 3;
    *(int4*)&Qs[r][c] = *(const int4*)(qb + (size_t)(ti * 128 + r) * 1024 + c);
    *(int4*)&Ks[r][c] = *(const int4*)(kb + (size_t)(tj * 128 + r) * 1024 + c);
  }
  __syncthreads();
  f32x4 acc[4][4] = {};
#pragma unroll
  for (int kk = 0; kk < 2; ++kk) {
    h8 af[4], bf[4];
#pragma unroll
    for (int mi = 0; mi < 4; ++mi) af[mi] = *(const h8*)&Qs[wr * 64 + mi * 16 + lr][kk * 32 + hi * 8];
#pragma unroll
    for (int ni = 0; ni < 4; ++ni) bf[ni] = *(const h8*)&Ks[wc * 64 + ni * 16 + lr][kk * 32 + hi * 8];
#pragma unroll
    for (int mi = 0; mi < 4; ++mi)
#pragma unroll
      for (int ni = 0; ni < 4; ++ni)
        acc[mi][ni] = MFMA16(af[mi], bf[ni], acc[mi][ni]);
  }
  float* ab = attn + ((size_t)bh * 512 + (size_t)ti * 128) * 512 + (size_t)tj * 128;
#pragma unroll
  for (int mi = 0; mi < 4; ++mi)
#pragma unroll
    for (int ni = 0; ni < 4; ++ni)
#pragma unroll
      for (int r = 0; r < 4; ++r) {
        int i = wr * 64 + mi * 16 + hi * 4 + r;
        int j = wc * 64 + ni * 16 + lr;
        int jglob = tj * 128 + j;
        float mterm = (1.0f - mask[b * 512 + jglob]) * (-1000000.0f);
        size_t o = (size_t)i * 512 + j;
        ab[o] = acc[mi][ni][r] * 0.125f + ab[o] + mterm;
      }
}

// ----------------- softmax per row; write fp16 P over row start -------------
__global__ __launch_bounds__(256) void softmax_kernel(float* __restrict__ attn) {
  int row = blockIdx.x * 4 + (threadIdx.x >> 6);
  int lane = threadIdx.x & 63;
  float* rp = attn + (size_t)row * 512;
  float4 v0 = *(const float4*)(rp + lane * 8);
  float4 v1 = *(const float4*)(rp + lane * 8 + 4);
  float vv[8] = {v0.x, v0.y, v0.z, v0.w, v1.x, v1.y, v1.z, v1.w};
  float m = vv[0];
#pragma unroll
  for (int u = 1; u < 8; ++u) m = fmaxf(m, vv[u]);
#pragma unroll
  for (int off = 32; off >= 1; off >>= 1) m = fmaxf(m, __shfl_xor(m, off, 64));
  float e[8];
  float s = 0.f;
#pragma unroll
  for (int u = 0; u < 8; ++u) { e[u] = __expf(vv[u] - m); s += e[u]; }
#pragma unroll
  for (int off = 32; off >= 1; off >>= 1) s += __shfl_xor(s, off, 64);
  float inv = 1.0f / s;
  h8 p;
#pragma unroll
  for (int u = 0; u < 8; ++u) p[u] = (_Float16)(e[u] * inv);
  _Float16* prow = (_Float16*)attn + (size_t)row * 1024;  // aliases rp; all reads done
  *(h8*)(prow + lane * 8) = p;
}

// ------------------------------- o = P @ V ----------------------------------
__global__ __launch_bounds__(256) void pv_kernel(
    const _Float16* __restrict__ P, const _Float16* __restrict__ vT,
    float* __restrict__ o32) {
  int bh = blockIdx.y, b = bh >> 4, h = bh & 15;
  int ti = blockIdx.x;  // 8 tiles of 64 rows
  __shared__ _Float16 Ps[64][40];
  __shared__ _Float16 Vs[64][40];
  int t = threadIdx.x, wid = t >> 6, lane = t & 63;
  int lr = lane & 15, hi = lane >> 4;
  const _Float16* Pb = P + ((size_t)bh * 512 + (size_t)ti * 64) * 1024;  // P row stride 1024 fp16
  const _Float16* Vb = vT + (size_t)bh * 64 * 512;
  f32x4 acc[4] = {};
  int r = t >> 2, c = (t & 3) << 3;
  for (int kt = 0; kt < 16; ++kt) {
    int k0 = kt * 32;
    *(int4*)&Ps[r][c] = *(const int4*)(Pb + (size_t)r * 1024 + k0 + c);
    *(int4*)&Vs[r][c] = *(const int4*)(Vb + (size_t)r * 512 + k0 + c);
    __syncthreads();
    h8 af = *(const h8*)&Ps[wid * 16 + lr][hi * 8];
    h8 bf[4];
#pragma unroll
    for (int ni = 0; ni < 4; ++ni) bf[ni] = *(const h8*)&Vs[ni * 16 + lr][hi * 8];
#pragma unroll
    for (int ni = 0; ni < 4; ++ni) acc[ni] = MFMA16(af, bf[ni], acc[ni]);
    __syncthreads();
  }
  float* ob = o32 + (size_t)b * 512 * 1024 + h * 64;
#pragma unroll
  for (int ni = 0; ni < 4; ++ni)
#pragma unroll
    for (int rr = 0; rr < 4; ++rr)
      ob[(size_t)(ti * 64 + wid * 16 + hi * 4 + rr) * 1024 + ni * 16 + lr] = acc[ni][rr];
}

// ------------------------------ x = fp16(g*o) -------------------------------
__global__ __launch_bounds__(256) void gx_kernel(
    const float* __restrict__ g, const float* __restrict__ o,
    _Float16* __restrict__ x, int n8) {
  int i = blockIdx.x * 256 + threadIdx.x;
  if (i >= n8) return;
  const float4* gp = (const float4*)g + (size_t)i * 2;
  const float4* op = (const float4*)o + (size_t)i * 2;
  float4 g0 = gp[0], g1 = gp[1], o0 = op[0], o1 = op[1];
  h8 v;
  v[0] = (_Float16)(g0.x * o0.x); v[1] = (_Float16)(g0.y * o0.y);
  v[2] = (_Float16)(g0.z * o0.z); v[3] = (_Float16)(g0.w * o0.w);
  v[4] = (_Float16)(g1.x * o1.x); v[5] = (_Float16)(g1.y * o1.y);
  v[6] = (_Float16)(g1.z * o1.z); v[7] = (_Float16)(g1.w * o1.w);
  *(h8*)(x + (size_t)i * 8) = v;
}

// ----------------------------------------------------------------------------
extern "C" void kernel_launch(void* const* d_in, const int* in_sizes, int n_in,
                              void* d_out, int out_size, void* d_ws, size_t ws_size,
                              hipStream_t stream) {
  const float* s    = (const float*)d_in[0];
  const float* z    = (const float*)d_in[1];
  const float* mask = (const float*)d_in[2];
  const float* kin  = (const float*)d_in[3];
  const float* wq   = (const float*)d_in[4];
  const float* bq   = (const float*)d_in[5];
  const float* wk   = (const float*)d_in[6];
  const float* wv   = (const float*)d_in[7];
  const float* wg   = (const float*)d_in[8];
  const float* lng  = (const float*)d_in[9];
  const float* lnb  = (const float*)d_in[10];
  const float* wz   = (const float*)d_in[11];
  const float* wo   = (const float*)d_in[12];
  float* out = (float*)d_out;

  char* ws = (char*)d_ws;
  _Float16* s16   = (_Float16*)(ws + OFF_S16);
  _Float16* kin16 = (_Float16*)(ws + OFF_KIN16);
  _Float16* wqT   = (_Float16*)(ws + OFF_WQT);
  _Float16* wkT   = (_Float16*)(ws + OFF_WKT);
  _Float16* wvT   = (_Float16*)(ws + OFF_WVT);
  _Float16* wgT   = (_Float16*)(ws + OFF_WGT);
  _Float16* woT   = (_Float16*)(ws + OFF_WOT);
  _Float16* q16   = (_Float16*)(ws + OFF_Q16);
  _Float16* k16   = (_Float16*)(ws + OFF_K16);
  _Float16* v16   = (_Float16*)(ws + OFF_V16);
  _Float16* vT16  = (_Float16*)(ws + OFF_VT16);
  _Float16* x16   = (_Float16*)(ws + OFF_X16);
  float* g32      = (float*)(ws + OFF_G32);
  float* o32      = (float*)(ws + OFF_O32);
  float* attn     = (float*)(ws + OFF_ATTN);

  conv_f16_kernel<<<512, 256, 0, stream>>>(s, s16, 131072);
  conv_f16_kernel<<<512, 256, 0, stream>>>(kin, kin16, 131072);
  convT_f16_kernel<<<dim3(256, 5), 256, 0, stream>>>(wq, wk, wv, wg, wo,
                                                     wqT, wkT, wvT, wgT, woT);
  ln_bias_kernel<<<dim3(8, 512, 2), 256, 0, stream>>>(z, lng, lnb, wz, attn);
  gemm_fused<<<dim3(64, 4), 256, 0, stream>>>(s16, kin16, x16, wqT, wkT, wvT, wgT,
                                              woT, bq, q16, k16, v16, g32, out, 0);
  transpose_v_kernel<<<512, 256, 0, stream>>>(v16, vT16);
  logits_kernel<<<dim3(16, 32), 256, 0, stream>>>(q16, k16, attn, mask);
  softmax_kernel<<<4096, 256, 0, stream>>>(attn);
  pv_kernel<<<dim3(8, 32), 256, 0, stream>>>((const _Float16*)attn, vT16, o32);
  gx_kernel<<<512, 256, 0, stream>>>(g32, o32, x16, 131072);
  gemm_fused<<<dim3(64, 1), 256, 0, stream>>>(s16, kin16, x16, wqT, wkT, wvT, wgT,
                                              woT, bq, q16, k16, v16, g32, out, 4);
}

// Round 2
// 180.044 us; speedup vs baseline: 1.2966x; 1.2966x over previous
//
#include <hip/hip_runtime.h>

// ---------------------------------------------------------------------------
// AttentionPairBias on MI355X (gfx950).
//   1. conv: s, k_in  fp32 -> fp16 (merged launch)
//   2. convT: wq,wk,wv,wg,wo fp32(K,N) -> fp16(N,K); y==5 slice precomputes
//      gwT16[16][128] (= ln_g*wz, transposed, fp16), G[16], bw[16]
//   3. ln_bias (MFMA): stats fp32 in regs during load; dot(z,gw) via
//      mfma_f32_16x16x32_f16; bias = rs*(dot - mu*G) + bw -> attn (B,H,N,N)
//   4. gemm_fused grid(64,4): q=s@wq+bq, k, v, g=sigmoid(s@wg)
//   5. transpose v -> vT (B,H,D,N), LDS-tiled + XOR swizzle
//   6. logits: attn = QK^T/8 + attn(bias) + (1-mask)*(-1e6)   (MFMA, RMW)
//   7. softmax per row (wave/row), writes fp16 P aliased over logits rows
//   8. pv: o = P@V (MFMA)
//   9. x = fp16(g*o)
//  10. gemm_o: 64x64 tiles, 256 blocks: out = x@wo (fp32)
// ---------------------------------------------------------------------------

typedef _Float16 h8 __attribute__((ext_vector_type(8)));
typedef _Float16 h4 __attribute__((ext_vector_type(4)));
typedef float f32x4 __attribute__((ext_vector_type(4)));

#define MFMA16(a, b, c) __builtin_amdgcn_mfma_f32_16x16x32_f16(a, b, c, 0, 0, 0)

// workspace layout (bytes), total 64 MiB
static constexpr size_t OFF_S16   = 0;          // 1M fp16
static constexpr size_t OFF_KIN16 = 2097152;
static constexpr size_t OFF_WQT   = 4194304;
static constexpr size_t OFF_WKT   = 6291456;
static constexpr size_t OFF_WVT   = 8388608;
static constexpr size_t OFF_WGT   = 10485760;
static constexpr size_t OFF_WOT   = 12582912;
static constexpr size_t OFF_Q16   = 14680064;
static constexpr size_t OFF_K16   = 16777216;
static constexpr size_t OFF_V16   = 18874368;
static constexpr size_t OFF_VT16  = 20971520;
static constexpr size_t OFF_X16   = 23068672;
static constexpr size_t OFF_G32   = 25165824;   // 1M fp32
static constexpr size_t OFF_GWT   = 29360128;   // 16x128 fp16 (4 KB)
static constexpr size_t OFF_GBW   = 29368320;   // 32 fp32
static constexpr size_t OFF_O32   = 29556736;   // 1M fp32 (4 MB)
static constexpr size_t OFF_ATTN  = 33554432;   // 2*16*512*512 fp32 = 32 MiB

// --------------------------- fp32 -> fp16 convert (s & kin) -----------------
__global__ __launch_bounds__(256) void conv_f16_kernel(
    const float* __restrict__ s, const float* __restrict__ kin,
    _Float16* __restrict__ s16, _Float16* __restrict__ kin16) {
  int blk = blockIdx.x;
  const float* in = (blk < 512) ? s : kin;
  _Float16* out = (blk < 512) ? s16 : kin16;
  int i = (blk & 511) * 256 + threadIdx.x;
  const float4* p = (const float4*)in + (size_t)i * 2;
  float4 a = p[0], b = p[1];
  h8 v;
  v[0] = (_Float16)a.x; v[1] = (_Float16)a.y; v[2] = (_Float16)a.z; v[3] = (_Float16)a.w;
  v[4] = (_Float16)b.x; v[5] = (_Float16)b.y; v[6] = (_Float16)b.z; v[7] = (_Float16)b.w;
  *(h8*)(out + (size_t)i * 8) = v;
}

// ------------- transpose-convert weights (K,N)->(N,K); y==5: prep gw --------
__global__ __launch_bounds__(256) void convT_f16_kernel(
    const float* __restrict__ w0, const float* __restrict__ w1,
    const float* __restrict__ w2, const float* __restrict__ w3,
    const float* __restrict__ w4,
    _Float16* __restrict__ o0, _Float16* __restrict__ o1,
    _Float16* __restrict__ o2, _Float16* __restrict__ o3,
    _Float16* __restrict__ o4,
    const float* __restrict__ lng, const float* __restrict__ lnb,
    const float* __restrict__ wz, _Float16* __restrict__ gwT,
    float* __restrict__ Gbw) {
  int t = threadIdx.x;
  if (blockIdx.y == 5) {  // prep gw: one block only
    if (blockIdx.x != 0) return;
    __shared__ float red[2][16][16];
    int h = t & 15, cg = t >> 4;  // 16 c-groups of 8
    float pg = 0.f, pb = 0.f;
#pragma unroll
    for (int u = 0; u < 8; ++u) {
      int c = cg * 8 + u;
      float w = wz[c * 16 + h];
      _Float16 gh = (_Float16)(lng[c] * w);
      gwT[h * 128 + c] = gh;
      pg += (float)gh;          // G from fp16-rounded gw (consistency)
      pb += lnb[c] * w;
    }
    red[0][h][cg] = pg; red[1][h][cg] = pb;
    __syncthreads();
    if (t < 32) {
      int hh = t & 15, which = t >> 4;
      float ssum = 0.f;
#pragma unroll
      for (int u = 0; u < 16; ++u) ssum += red[which][hh][u];
      Gbw[which * 16 + hh] = ssum;
    }
    return;
  }
  const float* w; _Float16* o;
  switch (blockIdx.y) {
    case 0: w = w0; o = o0; break;
    case 1: w = w1; o = o1; break;
    case 2: w = w2; o = o2; break;
    case 3: w = w3; o = o3; break;
    default: w = w4; o = o4; break;
  }
  int tile = blockIdx.x, tr = tile >> 4, tc = tile & 15;  // 16x16 tiles of 64
  __shared__ _Float16 ts[64][72];
#pragma unroll
  for (int p = 0; p < 4; ++p) {
    int e = p * 1024 + t * 4;
    int r = e >> 6, c = e & 63;
    float4 v = *(const float4*)(w + (size_t)(tr * 64 + r) * 1024 + tc * 64 + c);
    h4 hv;
    hv[0] = (_Float16)v.x; hv[1] = (_Float16)v.y; hv[2] = (_Float16)v.z; hv[3] = (_Float16)v.w;
    *(h4*)&ts[r][c] = hv;
  }
  __syncthreads();
#pragma unroll
  for (int p = 0; p < 4; ++p) {
    int e = p * 1024 + t * 4;
    int n = e >> 6, k = e & 63;
    h4 hv;
#pragma unroll
    for (int u = 0; u < 4; ++u) hv[u] = ts[k + u][n];
    *(h4*)(o + (size_t)(tc * 64 + n) * 1024 + tr * 64 + k) = hv;
  }
}

// --------------------- LayerNorm(z) @ wz  ->  bias buffer (MFMA) ------------
// bias[b,h,i,j] = rs_ij*(dot(z_ij, gw[:,h]) - mu_ij*G[h]) + bw[h]
__global__ __launch_bounds__(256) void ln_bias_kernel(
    const float* __restrict__ z, const _Float16* __restrict__ gwT,
    const float* __restrict__ Gbw, float* __restrict__ attn) {
  int jc = blockIdx.x, i = blockIdx.y, b = blockIdx.z;
  __shared__ _Float16 zh[64][136];   // pad 136: 2-way banks on frag reads
  __shared__ _Float16 gwh[16][136];
  __shared__ float mu_s[64], rs_s[64];
  __shared__ float Gs[16], bws[16];
  __shared__ float outs[64][17];
  int t = threadIdx.x;
  {  // stage gwT (2048 fp16) + G/bw
    int hh = t >> 4, cc = (t & 15) * 8;
    *(h8*)&gwh[hh][cc] = *(const h8*)(gwT + hh * 128 + cc);
    if (t < 32) { float v = Gbw[t]; if (t < 16) Gs[t] = v; else bws[t - 16] = v; }
  }
  const float* zb = z + (((size_t)b * 512 + i) * 512 + (size_t)jc * 64) * 128;
  int jj = t >> 2, q = t & 3;  // 4 threads per row
  const float* zr = zb + (size_t)jj * 128;
  float s1 = 0.f, s2 = 0.f;
#pragma unroll
  for (int u = 0; u < 8; ++u) {
    float4 v = *(const float4*)(zr + q * 4 + u * 16);
    s1 += v.x + v.y + v.z + v.w;
    s2 += v.x * v.x + v.y * v.y + v.z * v.z + v.w * v.w;
    h4 hv;
    hv[0] = (_Float16)v.x; hv[1] = (_Float16)v.y; hv[2] = (_Float16)v.z; hv[3] = (_Float16)v.w;
    *(h4*)&zh[jj][q * 4 + u * 16] = hv;
  }
  s1 += __shfl_xor(s1, 1, 64); s2 += __shfl_xor(s2, 1, 64);
  s1 += __shfl_xor(s1, 2, 64); s2 += __shfl_xor(s2, 2, 64);
  if (q == 0) {
    float mu = s1 * (1.0f / 128.0f);
    float var = s2 * (1.0f / 128.0f) - mu * mu;
    mu_s[jj] = mu;
    rs_s[jj] = rsqrtf(var + 1e-5f);
  }
  __syncthreads();
  // MFMA: wave w -> rows w*16..w*16+15, n = 16 heads, K = 128
  int wid = t >> 6, lane = t & 63, lr = lane & 15, hi = lane >> 4;
  f32x4 acc = {};
#pragma unroll
  for (int kk = 0; kk < 4; ++kk) {
    h8 af = *(const h8*)&zh[wid * 16 + lr][kk * 32 + hi * 8];
    h8 bf = *(const h8*)&gwh[lr][kk * 32 + hi * 8];
    acc = MFMA16(af, bf, acc);
  }
#pragma unroll
  for (int r = 0; r < 4; ++r) {
    int row = wid * 16 + hi * 4 + r;  // jj
    outs[row][lr] = rs_s[row] * (acc[r] - mu_s[row] * Gs[lr]) + bws[lr];
  }
  __syncthreads();
  {  // coalesced plane writes: thread t -> head t>>4, 4 consecutive j
    int h = t >> 4, j0 = (t & 15) * 4;
    float4 o;
    o.x = outs[j0 + 0][h]; o.y = outs[j0 + 1][h];
    o.z = outs[j0 + 2][h]; o.w = outs[j0 + 3][h];
    *(float4*)(attn + (((size_t)(b * 16 + h) * 512) + i) * 512 + (size_t)jc * 64 + j0) = o;
  }
}

// ------------------------ fused 1024^3 GEMMs (MFMA fp16) --------------------
// mode 0: q=s@wq+bq  1: k=kin@wk  2: v=kin@wv  3: g=sigmoid(s@wg)
__global__ __launch_bounds__(256) void gemm_fused(
    const _Float16* __restrict__ s16, const _Float16* __restrict__ kin16,
    const _Float16* __restrict__ wqT, const _Float16* __restrict__ wkT,
    const _Float16* __restrict__ wvT, const _Float16* __restrict__ wgT,
    const float* __restrict__ bq,
    _Float16* __restrict__ q16, _Float16* __restrict__ k16,
    _Float16* __restrict__ v16, float* __restrict__ g32) {
  int mode = blockIdx.y;
  const _Float16 *A, *BT;
  switch (mode) {
    case 0: A = s16;   BT = wqT; break;
    case 1: A = kin16; BT = wkT; break;
    case 2: A = kin16; BT = wvT; break;
    default: A = s16;  BT = wgT; break;
  }
  int tile = blockIdx.x, bm = tile >> 3, bn = tile & 7;
  __shared__ _Float16 As[128][40];
  __shared__ _Float16 Bs[128][40];
  int t = threadIdx.x, wid = t >> 6, lane = t & 63;
  int wr = wid >> 1, wc = wid & 1;
  int lr = lane & 15, hi = lane >> 4;
  f32x4 acc[4][4] = {};
  for (int kt = 0; kt < 32; ++kt) {
    int k0 = kt * 32;
#pragma unroll
    for (int p = 0; p < 2; ++p) {
      int idx = p * 256 + t;
      int r = idx >> 2, c = (idx & 3) << 3;
      int4 da = *(const int4*)(A + (size_t)(bm * 128 + r) * 1024 + k0 + c);
      int4 db = *(const int4*)(BT + (size_t)(bn * 128 + r) * 1024 + k0 + c);
      *(int4*)&As[r][c] = da;
      *(int4*)&Bs[r][c] = db;
    }
    __syncthreads();
    h8 af[4], bf[4];
#pragma unroll
    for (int mi = 0; mi < 4; ++mi) af[mi] = *(const h8*)&As[wr * 64 + mi * 16 + lr][hi * 8];
#pragma unroll
    for (int ni = 0; ni < 4; ++ni) bf[ni] = *(const h8*)&Bs[wc * 64 + ni * 16 + lr][hi * 8];
#pragma unroll
    for (int mi = 0; mi < 4; ++mi)
#pragma unroll
      for (int ni = 0; ni < 4; ++ni)
        acc[mi][ni] = MFMA16(af[mi], bf[ni], acc[mi][ni]);
    __syncthreads();
  }
#pragma unroll
  for (int mi = 0; mi < 4; ++mi)
#pragma unroll
    for (int ni = 0; ni < 4; ++ni)
#pragma unroll
      for (int r = 0; r < 4; ++r) {
        int row = bm * 128 + wr * 64 + mi * 16 + hi * 4 + r;
        int col = bn * 128 + wc * 64 + ni * 16 + lr;
        float v = acc[mi][ni][r];
        size_t o = (size_t)row * 1024 + col;
        switch (mode) {
          case 0: q16[o] = (_Float16)(v + bq[col]); break;
          case 1: k16[o] = (_Float16)v; break;
          case 2: v16[o] = (_Float16)v; break;
          default: g32[o] = 1.0f / (1.0f + __expf(-v)); break;
        }
      }
}

// ------------- v (B,N,H,D) -> vT (B,H,D,N), LDS tile + XOR swizzle ----------
__global__ __launch_bounds__(256) void transpose_v_kernel(
    const _Float16* __restrict__ v16, _Float16* __restrict__ vT) {
  int jt = blockIdx.x, bh = blockIdx.y, b = bh >> 4, h = bh & 15;
  __shared__ _Float16 ts[64][72];
  int t = threadIdx.x;
  const _Float16* src = v16 + ((size_t)b * 512 + (size_t)jt * 64) * 1024 + h * 64;
#pragma unroll
  for (int p = 0; p < 2; ++p) {
    int r = p * 32 + (t >> 3), c = (t & 7) * 8;
    *(int4*)&ts[r][c ^ (((r >> 3) & 7) << 3)] = *(const int4*)(src + (size_t)r * 1024 + c);
  }
  __syncthreads();
#pragma unroll
  for (int p = 0; p < 2; ++p) {
    int d = p * 32 + (t >> 3), j0 = (t & 7) * 8;
    h8 v;
#pragma unroll
    for (int u = 0; u < 8; ++u) {
      int j = j0 + u;
      v[u] = ts[j][d ^ (((j >> 3) & 7) << 3)];
    }
    *(h8*)(vT + ((size_t)bh * 64 + d) * 512 + (size_t)jt * 64 + j0) = v;
  }
}

// --------------------- logits = QK^T/8 + bias + mask (MFMA) -----------------
__global__ __launch_bounds__(256) void logits_kernel(
    const _Float16* __restrict__ q16, const _Float16* __restrict__ k16,
    float* __restrict__ attn, const float* __restrict__ mask) {
  int bh = blockIdx.y, b = bh >> 4, h = bh & 15;
  int tile = blockIdx.x, ti = tile >> 2, tj = tile & 3;
  __shared__ _Float16 Qs[128][72];
  __shared__ _Float16 Ks[128][72];
  int t = threadIdx.x, wid = t >> 6, lane = t & 63;
  int wr = wid >> 1, wc = wid & 1, lr = lane & 15, hi = lane >> 4;
  const _Float16* qb = q16 + ((size_t)b * 512) * 1024 + h * 64;
  const _Float16* kb = k16 + ((size_t)b * 512) * 1024 + h * 64;
#pragma unroll
  for (int p = 0; p < 4; ++p) {
    int idx = p * 256 + t;
    int r = idx >> 3, c = (idx & 7) << 3;
    *(int4*)&Qs[r][c] = *(const int4*)(qb + (size_t)(ti * 128 + r) * 1024 + c);
    *(int4*)&Ks[r][c] = *(const int4*)(kb + (size_t)(tj * 128 + r) * 1024 + c);
  }
  __syncthreads();
  f32x4 acc[4][4] = {};
#pragma unroll
  for (int kk = 0; kk < 2; ++kk) {
    h8 af[4], bf[4];
#pragma unroll
    for (int mi = 0; mi < 4; ++mi) af[mi] = *(const h8*)&Qs[wr * 64 + mi * 16 + lr][kk * 32 + hi * 8];
#pragma unroll
    for (int ni = 0; ni < 4; ++ni) bf[ni] = *(const h8*)&Ks[wc * 64 + ni * 16 + lr][kk * 32 + hi * 8];
#pragma unroll
    for (int mi = 0; mi < 4; ++mi)
#pragma unroll
      for (int ni = 0; ni < 4; ++ni)
        acc[mi][ni] = MFMA16(af[mi], bf[ni], acc[mi][ni]);
  }
  float* ab = attn + ((size_t)bh * 512 + (size_t)ti * 128) * 512 + (size_t)tj * 128;
#pragma unroll
  for (int mi = 0; mi < 4; ++mi)
#pragma unroll
    for (int ni = 0; ni < 4; ++ni)
#pragma unroll
      for (int r = 0; r < 4; ++r) {
        int i = wr * 64 + mi * 16 + hi * 4 + r;
        int j = wc * 64 + ni * 16 + lr;
        int jglob = tj * 128 + j;
        float mterm = (1.0f - mask[b * 512 + jglob]) * (-1000000.0f);
        size_t o = (size_t)i * 512 + j;
        ab[o] = acc[mi][ni][r] * 0.125f + ab[o] + mterm;
      }
}

// ----------------- softmax per row; write fp16 P over row start -------------
__global__ __launch_bounds__(256) void softmax_kernel(float* __restrict__ attn) {
  int row = blockIdx.x * 4 + (threadIdx.x >> 6);
  int lane = threadIdx.x & 63;
  float* rp = attn + (size_t)row * 512;
  float4 v0 = *(const float4*)(rp + lane * 8);
  float4 v1 = *(const float4*)(rp + lane * 8 + 4);
  float vv[8] = {v0.x, v0.y, v0.z, v0.w, v1.x, v1.y, v1.z, v1.w};
  float m = vv[0];
#pragma unroll
  for (int u = 1; u < 8; ++u) m = fmaxf(m, vv[u]);
#pragma unroll
  for (int off = 32; off >= 1; off >>= 1) m = fmaxf(m, __shfl_xor(m, off, 64));
  float e[8];
  float s = 0.f;
#pragma unroll
  for (int u = 0; u < 8; ++u) { e[u] = __expf(vv[u] - m); s += e[u]; }
#pragma unroll
  for (int off = 32; off >= 1; off >>= 1) s += __shfl_xor(s, off, 64);
  float inv = 1.0f / s;
  h8 p;
#pragma unroll
  for (int u = 0; u < 8; ++u) p[u] = (_Float16)(e[u] * inv);
  _Float16* prow = (_Float16*)attn + (size_t)row * 1024;  // aliases rp; reads done
  *(h8*)(prow + lane * 8) = p;
}

// ------------------------------- o = P @ V ----------------------------------
__global__ __launch_bounds__(256) void pv_kernel(
    const _Float16* __restrict__ P, const _Float16* __restrict__ vT,
    float* __restrict__ o32) {
  int bh = blockIdx.y, b = bh >> 4, h = bh & 15;
  int ti = blockIdx.x;  // 8 tiles of 64 rows
  __shared__ _Float16 Ps[64][40];
  __shared__ _Float16 Vs[64][40];
  int t = threadIdx.x, wid = t >> 6, lane = t & 63;
  int lr = lane & 15, hi = lane >> 4;
  const _Float16* Pb = P + ((size_t)bh * 512 + (size_t)ti * 64) * 1024;
  const _Float16* Vb = vT + (size_t)bh * 64 * 512;
  f32x4 acc[4] = {};
  int r = t >> 2, c = (t & 3) << 3;
  for (int kt = 0; kt < 16; ++kt) {
    int k0 = kt * 32;
    *(int4*)&Ps[r][c] = *(const int4*)(Pb + (size_t)r * 1024 + k0 + c);
    *(int4*)&Vs[r][c] = *(const int4*)(Vb + (size_t)r * 512 + k0 + c);
    __syncthreads();
    h8 af = *(const h8*)&Ps[wid * 16 + lr][hi * 8];
    h8 bf[4];
#pragma unroll
    for (int ni = 0; ni < 4; ++ni) bf[ni] = *(const h8*)&Vs[ni * 16 + lr][hi * 8];
#pragma unroll
    for (int ni = 0; ni < 4; ++ni) acc[ni] = MFMA16(af, bf[ni], acc[ni]);
    __syncthreads();
  }
  float* ob = o32 + (size_t)b * 512 * 1024 + h * 64;
#pragma unroll
  for (int ni = 0; ni < 4; ++ni)
#pragma unroll
    for (int rr = 0; rr < 4; ++rr)
      ob[(size_t)(ti * 64 + wid * 16 + hi * 4 + rr) * 1024 + ni * 16 + lr] = acc[ni][rr];
}

// ------------------------------ x = fp16(g*o) -------------------------------
__global__ __launch_bounds__(256) void gx_kernel(
    const float* __restrict__ g, const float* __restrict__ o,
    _Float16* __restrict__ x) {
  int i = blockIdx.x * 256 + threadIdx.x;
  const float4* gp = (const float4*)g + (size_t)i * 2;
  const float4* op = (const float4*)o + (size_t)i * 2;
  float4 g0 = gp[0], g1 = gp[1], o0 = op[0], o1 = op[1];
  h8 v;
  v[0] = (_Float16)(g0.x * o0.x); v[1] = (_Float16)(g0.y * o0.y);
  v[2] = (_Float16)(g0.z * o0.z); v[3] = (_Float16)(g0.w * o0.w);
  v[4] = (_Float16)(g1.x * o1.x); v[5] = (_Float16)(g1.y * o1.y);
  v[6] = (_Float16)(g1.z * o1.z); v[7] = (_Float16)(g1.w * o1.w);
  *(h8*)(x + (size_t)i * 8) = v;
}

// --------------------- out = x @ wo, 64x64 tiles (256 blocks) ---------------
__global__ __launch_bounds__(256) void gemm_o_kernel(
    const _Float16* __restrict__ x16, const _Float16* __restrict__ woT,
    float* __restrict__ out32) {
  int bm = blockIdx.x >> 4, bn = blockIdx.x & 15;
  __shared__ _Float16 As[64][72];
  __shared__ _Float16 Bs[64][72];
  int t = threadIdx.x, wid = t >> 6, lane = t & 63;
  int wr = wid >> 1, wc = wid & 1;  // wave covers 32x32
  int lr = lane & 15, hi = lane >> 4;
  f32x4 acc[2][2] = {};
  for (int kt = 0; kt < 16; ++kt) {
    int k0 = kt * 64;
#pragma unroll
    for (int p = 0; p < 2; ++p) {
      int r = p * 32 + (t >> 3), c = (t & 7) * 8;
      *(int4*)&As[r][c] = *(const int4*)(x16 + (size_t)(bm * 64 + r) * 1024 + k0 + c);
      *(int4*)&Bs[r][c] = *(const int4*)(woT + (size_t)(bn * 64 + r) * 1024 + k0 + c);
    }
    __syncthreads();
#pragma unroll
    for (int kk = 0; kk < 2; ++kk) {
      h8 af[2], bf[2];
#pragma unroll
      for (int mi = 0; mi < 2; ++mi) af[mi] = *(const h8*)&As[wr * 32 + mi * 16 + lr][kk * 32 + hi * 8];
#pragma unroll
      for (int ni = 0; ni < 2; ++ni) bf[ni] = *(const h8*)&Bs[wc * 32 + ni * 16 + lr][kk * 32 + hi * 8];
#pragma unroll
      for (int mi = 0; mi < 2; ++mi)
#pragma unroll
        for (int ni = 0; ni < 2; ++ni)
          acc[mi][ni] = MFMA16(af[mi], bf[ni], acc[mi][ni]);
    }
    __syncthreads();
  }
#pragma unroll
  for (int mi = 0; mi < 2; ++mi)
#pragma unroll
    for (int ni = 0; ni < 2; ++ni)
#pragma unroll
      for (int r = 0; r < 4; ++r) {
        int row = bm * 64 + wr * 32 + mi * 16 + hi * 4 + r;
        int col = bn * 64 + wc * 32 + ni * 16 + lr;
        out32[(size_t)row * 1024 + col] = acc[mi][ni][r];
      }
}

// ----------------------------------------------------------------------------
extern "C" void kernel_launch(void* const* d_in, const int* in_sizes, int n_in,
                              void* d_out, int out_size, void* d_ws, size_t ws_size,
                              hipStream_t stream) {
  const float* s    = (const float*)d_in[0];
  const float* z    = (const float*)d_in[1];
  const float* mask = (const float*)d_in[2];
  const float* kin  = (const float*)d_in[3];
  const float* wq   = (const float*)d_in[4];
  const float* bq   = (const float*)d_in[5];
  const float* wk   = (const float*)d_in[6];
  const float* wv   = (const float*)d_in[7];
  const float* wg   = (const float*)d_in[8];
  const float* lng  = (const float*)d_in[9];
  const float* lnb  = (const float*)d_in[10];
  const float* wz   = (const float*)d_in[11];
  const float* wo   = (const float*)d_in[12];
  float* out = (float*)d_out;

  char* ws = (char*)d_ws;
  _Float16* s16   = (_Float16*)(ws + OFF_S16);
  _Float16* kin16 = (_Float16*)(ws + OFF_KIN16);
  _Float16* wqT   = (_Float16*)(ws + OFF_WQT);
  _Float16* wkT   = (_Float16*)(ws + OFF_WKT);
  _Float16* wvT   = (_Float16*)(ws + OFF_WVT);
  _Float16* wgT   = (_Float16*)(ws + OFF_WGT);
  _Float16* woT   = (_Float16*)(ws + OFF_WOT);
  _Float16* q16   = (_Float16*)(ws + OFF_Q16);
  _Float16* k16   = (_Float16*)(ws + OFF_K16);
  _Float16* v16   = (_Float16*)(ws + OFF_V16);
  _Float16* vT16  = (_Float16*)(ws + OFF_VT16);
  _Float16* x16   = (_Float16*)(ws + OFF_X16);
  float* g32      = (float*)(ws + OFF_G32);
  _Float16* gwT   = (_Float16*)(ws + OFF_GWT);
  float* Gbw      = (float*)(ws + OFF_GBW);
  float* o32      = (float*)(ws + OFF_O32);
  float* attn     = (float*)(ws + OFF_ATTN);

  conv_f16_kernel<<<1024, 256, 0, stream>>>(s, kin, s16, kin16);
  convT_f16_kernel<<<dim3(256, 6), 256, 0, stream>>>(wq, wk, wv, wg, wo,
                                                     wqT, wkT, wvT, wgT, woT,
                                                     lng, lnb, wz, gwT, Gbw);
  ln_bias_kernel<<<dim3(8, 512, 2), 256, 0, stream>>>(z, gwT, Gbw, attn);
  gemm_fused<<<dim3(64, 4), 256, 0, stream>>>(s16, kin16, wqT, wkT, wvT, wgT,
                                              bq, q16, k16, v16, g32);
  transpose_v_kernel<<<dim3(8, 32), 256, 0, stream>>>(v16, vT16);
  logits_kernel<<<dim3(16, 32), 256, 0, stream>>>(q16, k16, attn, mask);
  softmax_kernel<<<4096, 256, 0, stream>>>(attn);
  pv_kernel<<<dim3(8, 32), 256, 0, stream>>>((const _Float16*)attn, vT16, o32);
  gx_kernel<<<512, 256, 0, stream>>>(g32, o32, x16);
  gemm_o_kernel<<<256, 256, 0, stream>>>(x16, woT, out);
}

// Round 4
// 131.960 us; speedup vs baseline: 1.7691x; 1.3644x over previous
//
#include <hip/hip_runtime.h>

// ---------------------------------------------------------------------------
// AttentionPairBias on MI355X (gfx950).
//   1. conv: s, k_in fp32 -> fp16
//   2. convT: wq,wk,wv,wg,wo fp32(K,N)->fp16(N,K); y==5 precomputes gwT/G/bw
//   3. ln_bias (MFMA): bias16[b,h,i,j] fp16 (16.8 MB)
//   4. gemm_fused grid(64,4), 128^2 tiles, BK=64, global_load_lds staging with
//      source-side XOR swizzle: q=(s@wq+bq)/8, k, v, g=sigmoid(s@wg)
//   5. transpose v -> vT (B,H,D,N)
//   6. flash: per (bh, 64 i): swapped QK^T (mfma(K,Q)) + bias + mask,
//      in-register softmax over j (shfl_xor 16/32), P->fp16 pack,
//      shfl-redistribute to PV A-frags, PV MFMA, epilogue x16 = fp16(g*o)
//   7. gemm_o: 64^2 tiles x 256 blocks, BK=64, gload_lds: out = x@wo (fp32)
// ---------------------------------------------------------------------------

typedef _Float16 h8 __attribute__((ext_vector_type(8)));
typedef _Float16 h4 __attribute__((ext_vector_type(4)));
typedef float f32x4 __attribute__((ext_vector_type(4)));
typedef unsigned int u32;

#define MFMA16(a, b, c) __builtin_amdgcn_mfma_f32_16x16x32_f16(a, b, c, 0, 0, 0)

// pack two fp32 -> fp16x2 (RTZ), as u32
__device__ __forceinline__ u32 pkrtz(float a, float b) {
  return __builtin_bit_cast(u32, __builtin_amdgcn_cvt_pkrtz(a, b));
}

// async global->LDS, 16B per lane; lds dst = wave-uniform base + lane*16
__device__ __forceinline__ void gl_lds16(const void* g, void* l) {
  __builtin_amdgcn_global_load_lds(
      (const __attribute__((address_space(1))) u32*)g,
      (__attribute__((address_space(3))) u32*)l, 16, 0, 0);
}

// workspace layout (bytes)
static constexpr size_t OFF_S16   = 0;          // 1M fp16
static constexpr size_t OFF_KIN16 = 2097152;
static constexpr size_t OFF_WQT   = 4194304;
static constexpr size_t OFF_WKT   = 6291456;
static constexpr size_t OFF_WVT   = 8388608;
static constexpr size_t OFF_WGT   = 10485760;
static constexpr size_t OFF_WOT   = 12582912;
static constexpr size_t OFF_Q16   = 14680064;
static constexpr size_t OFF_K16   = 16777216;
static constexpr size_t OFF_V16   = 18874368;
static constexpr size_t OFF_VT16  = 20971520;
static constexpr size_t OFF_X16   = 23068672;
static constexpr size_t OFF_G32   = 25165824;   // 1M fp32
static constexpr size_t OFF_GWT   = 29360128;   // 16x128 fp16
static constexpr size_t OFF_GBW   = 29368320;   // 32 fp32
static constexpr size_t OFF_BIAS  = 33554432;   // 2*16*512*512 fp16 = 16 MiB

// --------------------------- fp32 -> fp16 convert (s & kin) -----------------
__global__ __launch_bounds__(256) void conv_f16_kernel(
    const float* __restrict__ s, const float* __restrict__ kin,
    _Float16* __restrict__ s16, _Float16* __restrict__ kin16) {
  int blk = blockIdx.x;
  const float* in = (blk < 512) ? s : kin;
  _Float16* out = (blk < 512) ? s16 : kin16;
  int i = (blk & 511) * 256 + threadIdx.x;
  const float4* p = (const float4*)in + (size_t)i * 2;
  float4 a = p[0], b = p[1];
  h8 v;
  v[0] = (_Float16)a.x; v[1] = (_Float16)a.y; v[2] = (_Float16)a.z; v[3] = (_Float16)a.w;
  v[4] = (_Float16)b.x; v[5] = (_Float16)b.y; v[6] = (_Float16)b.z; v[7] = (_Float16)b.w;
  *(h8*)(out + (size_t)i * 8) = v;
}

// ------------- transpose-convert weights (K,N)->(N,K); y==5: prep gw --------
__global__ __launch_bounds__(256) void convT_f16_kernel(
    const float* __restrict__ w0, const float* __restrict__ w1,
    const float* __restrict__ w2, const float* __restrict__ w3,
    const float* __restrict__ w4,
    _Float16* __restrict__ o0, _Float16* __restrict__ o1,
    _Float16* __restrict__ o2, _Float16* __restrict__ o3,
    _Float16* __restrict__ o4,
    const float* __restrict__ lng, const float* __restrict__ lnb,
    const float* __restrict__ wz, _Float16* __restrict__ gwT,
    float* __restrict__ Gbw) {
  int t = threadIdx.x;
  if (blockIdx.y == 5) {  // prep gw
    if (blockIdx.x != 0) return;
    __shared__ float red[2][16][16];
    int h = t & 15, cg = t >> 4;
    float pg = 0.f, pb = 0.f;
#pragma unroll
    for (int u = 0; u < 8; ++u) {
      int c = cg * 8 + u;
      float w = wz[c * 16 + h];
      _Float16 gh = (_Float16)(lng[c] * w);
      gwT[h * 128 + c] = gh;
      pg += (float)gh;
      pb += lnb[c] * w;
    }
    red[0][h][cg] = pg; red[1][h][cg] = pb;
    __syncthreads();
    if (t < 32) {
      int hh = t & 15, which = t >> 4;
      float ssum = 0.f;
#pragma unroll
      for (int u = 0; u < 16; ++u) ssum += red[which][hh][u];
      Gbw[which * 16 + hh] = ssum;
    }
    return;
  }
  const float* w; _Float16* o;
  switch (blockIdx.y) {
    case 0: w = w0; o = o0; break;
    case 1: w = w1; o = o1; break;
    case 2: w = w2; o = o2; break;
    case 3: w = w3; o = o3; break;
    default: w = w4; o = o4; break;
  }
  int tile = blockIdx.x, tr = tile >> 4, tc = tile & 15;
  __shared__ _Float16 ts[64][72];
#pragma unroll
  for (int p = 0; p < 4; ++p) {
    int e = p * 1024 + t * 4;
    int r = e >> 6, c = e & 63;
    float4 v = *(const float4*)(w + (size_t)(tr * 64 + r) * 1024 + tc * 64 + c);
    h4 hv;
    hv[0] = (_Float16)v.x; hv[1] = (_Float16)v.y; hv[2] = (_Float16)v.z; hv[3] = (_Float16)v.w;
    *(h4*)&ts[r][c] = hv;
  }
  __syncthreads();
#pragma unroll
  for (int p = 0; p < 4; ++p) {
    int e = p * 1024 + t * 4;
    int n = e >> 6, k = e & 63;
    h4 hv;
#pragma unroll
    for (int u = 0; u < 4; ++u) hv[u] = ts[k + u][n];
    *(h4*)(o + (size_t)(tc * 64 + n) * 1024 + tr * 64 + k) = hv;
  }
}

// --------------------- LayerNorm(z) @ wz -> bias16 (MFMA) -------------------
__global__ __launch_bounds__(256) void ln_bias_kernel(
    const float* __restrict__ z, const _Float16* __restrict__ gwT,
    const float* __restrict__ Gbw, _Float16* __restrict__ bias16) {
  int jc = blockIdx.x, i = blockIdx.y, b = blockIdx.z;
  __shared__ _Float16 zh[64][136];
  __shared__ _Float16 gwh[16][136];
  __shared__ float mu_s[64], rs_s[64];
  __shared__ float Gs[16], bws[16];
  __shared__ float outs[64][17];
  int t = threadIdx.x;
  {
    int hh = t >> 4, cc = (t & 15) * 8;
    *(h8*)&gwh[hh][cc] = *(const h8*)(gwT + hh * 128 + cc);
    if (t < 32) { float v = Gbw[t]; if (t < 16) Gs[t] = v; else bws[t - 16] = v; }
  }
  const float* zb = z + (((size_t)b * 512 + i) * 512 + (size_t)jc * 64) * 128;
  int jj = t >> 2, q = t & 3;
  const float* zr = zb + (size_t)jj * 128;
  float s1 = 0.f, s2 = 0.f;
#pragma unroll
  for (int u = 0; u < 8; ++u) {
    float4 v = *(const float4*)(zr + q * 4 + u * 16);
    s1 += v.x + v.y + v.z + v.w;
    s2 += v.x * v.x + v.y * v.y + v.z * v.z + v.w * v.w;
    h4 hv;
    hv[0] = (_Float16)v.x; hv[1] = (_Float16)v.y; hv[2] = (_Float16)v.z; hv[3] = (_Float16)v.w;
    *(h4*)&zh[jj][q * 4 + u * 16] = hv;
  }
  s1 += __shfl_xor(s1, 1, 64); s2 += __shfl_xor(s2, 1, 64);
  s1 += __shfl_xor(s1, 2, 64); s2 += __shfl_xor(s2, 2, 64);
  if (q == 0) {
    float mu = s1 * (1.0f / 128.0f);
    float var = s2 * (1.0f / 128.0f) - mu * mu;
    mu_s[jj] = mu;
    rs_s[jj] = rsqrtf(var + 1e-5f);
  }
  __syncthreads();
  int wid = t >> 6, lane = t & 63, lr = lane & 15, hi = lane >> 4;
  f32x4 acc = {};
#pragma unroll
  for (int kk = 0; kk < 4; ++kk) {
    h8 af = *(const h8*)&zh[wid * 16 + lr][kk * 32 + hi * 8];
    h8 bf = *(const h8*)&gwh[lr][kk * 32 + hi * 8];
    acc = MFMA16(af, bf, acc);
  }
#pragma unroll
  for (int r = 0; r < 4; ++r) {
    int row = wid * 16 + hi * 4 + r;
    outs[row][lr] = rs_s[row] * (acc[r] - mu_s[row] * Gs[lr]) + bws[lr];
  }
  __syncthreads();
  {
    int hh = t >> 4, j0w = (t & 15) * 4;
    h4 ov;
    ov[0] = (_Float16)outs[j0w + 0][hh]; ov[1] = (_Float16)outs[j0w + 1][hh];
    ov[2] = (_Float16)outs[j0w + 2][hh]; ov[3] = (_Float16)outs[j0w + 3][hh];
    *(h4*)(bias16 + (((size_t)(b * 16 + hh) * 512) + i) * 512 + (size_t)jc * 64 + j0w) = ov;
  }
}

// ------------- fused 1024^3 GEMMs: 128^2 tile, BK=64, gload_lds -------------
// mode 0: q=(s@wq+bq)/8  1: k=kin@wk  2: v=kin@wv  3: g=sigmoid(s@wg)
__global__ __launch_bounds__(256) void gemm_fused(
    const _Float16* __restrict__ s16, const _Float16* __restrict__ kin16,
    const _Float16* __restrict__ wqT, const _Float16* __restrict__ wkT,
    const _Float16* __restrict__ wvT, const _Float16* __restrict__ wgT,
    const float* __restrict__ bq,
    _Float16* __restrict__ q16, _Float16* __restrict__ k16,
    _Float16* __restrict__ v16, float* __restrict__ g32) {
  int mode = blockIdx.y;
  const _Float16 *A, *BT;
  switch (mode) {
    case 0: A = s16;   BT = wqT; break;
    case 1: A = kin16; BT = wkT; break;
    case 2: A = kin16; BT = wvT; break;
    default: A = s16;  BT = wgT; break;
  }
  int bm = blockIdx.x >> 3, bn = blockIdx.x & 7;
  __shared__ _Float16 As[2][128 * 64];
  __shared__ _Float16 Bs[2][128 * 64];
  int t = threadIdx.x, wid = t >> 6, lane = t & 63;
  int wr = wid >> 1, wc = wid & 1, lr = lane & 15, hi = lane >> 4;
  const _Float16* Ab = A + (size_t)(bm * 128) * 1024;
  const _Float16* Bb = BT + (size_t)(bn * 128) * 1024;

  auto STAGE = [&](int kt, int buf) {
    int k0 = kt * 64;
#pragma unroll
    for (int p = 0; p < 4; ++p) {
      int q = (wid * 4 + p) * 64 + lane;   // 16B-unit index, 0..1023
      int row = q >> 3, c16 = q & 7;
      int coff = (c16 * 16) ^ ((row & 7) << 4);
      gl_lds16(Ab + (size_t)row * 1024 + k0 + (coff >> 1),
               (char*)As[buf] + (wid * 4 + p) * 1024);
      gl_lds16(Bb + (size_t)row * 1024 + k0 + (coff >> 1),
               (char*)Bs[buf] + (wid * 4 + p) * 1024);
    }
  };

  f32x4 acc[4][4] = {};
  STAGE(0, 0);
  __syncthreads();
  for (int kt = 0; kt < 16; ++kt) {
    int buf = kt & 1;
    if (kt < 15) STAGE(kt + 1, buf ^ 1);
#pragma unroll
    for (int kk = 0; kk < 2; ++kk) {
      h8 af[4], bf[4];
#pragma unroll
      for (int mi = 0; mi < 4; ++mi) {
        int row = wr * 64 + mi * 16 + lr;
        af[mi] = *(const h8*)((char*)As[buf] + row * 128 + ((kk * 64 + hi * 16) ^ ((lr & 7) << 4)));
      }
#pragma unroll
      for (int ni = 0; ni < 4; ++ni) {
        int row = wc * 64 + ni * 16 + lr;
        bf[ni] = *(const h8*)((char*)Bs[buf] + row * 128 + ((kk * 64 + hi * 16) ^ ((lr & 7) << 4)));
      }
#pragma unroll
      for (int mi = 0; mi < 4; ++mi)
#pragma unroll
        for (int ni = 0; ni < 4; ++ni)
          acc[mi][ni] = MFMA16(af[mi], bf[ni], acc[mi][ni]);
    }
    __syncthreads();
  }
#pragma unroll
  for (int mi = 0; mi < 4; ++mi)
#pragma unroll
    for (int ni = 0; ni < 4; ++ni)
#pragma unroll
      for (int r = 0; r < 4; ++r) {
        int row = bm * 128 + wr * 64 + mi * 16 + hi * 4 + r;
        int col = bn * 128 + wc * 64 + ni * 16 + lr;
        float v = acc[mi][ni][r];
        size_t o = (size_t)row * 1024 + col;
        switch (mode) {
          case 0: q16[o] = (_Float16)((v + bq[col]) * 0.125f); break;
          case 1: k16[o] = (_Float16)v; break;
          case 2: v16[o] = (_Float16)v; break;
          default: g32[o] = 1.0f / (1.0f + __expf(-v)); break;
        }
      }
}

// ------------- v (B,N,H,D) -> vT (B,H,D,N), LDS tile + XOR swizzle ----------
__global__ __launch_bounds__(256) void transpose_v_kernel(
    const _Float16* __restrict__ v16, _Float16* __restrict__ vT) {
  int jt = blockIdx.x, bh = blockIdx.y, b = bh >> 4, h = bh & 15;
  __shared__ _Float16 ts[64][72];
  int t = threadIdx.x;
  const _Float16* src = v16 + ((size_t)b * 512 + (size_t)jt * 64) * 1024 + h * 64;
#pragma unroll
  for (int p = 0; p < 2; ++p) {
    int r = p * 32 + (t >> 3), c = (t & 7) * 8;
    *(int4*)&ts[r][c ^ (((r >> 3) & 7) << 3)] = *(const int4*)(src + (size_t)r * 1024 + c);
  }
  __syncthreads();
#pragma unroll
  for (int p = 0; p < 2; ++p) {
    int d = p * 32 + (t >> 3), j0 = (t & 7) * 8;
    h8 v;
#pragma unroll
    for (int u = 0; u < 8; ++u) {
      int j = j0 + u;
      v[u] = ts[j][d ^ (((j >> 3) & 7) << 3)];
    }
    *(h8*)(vT + ((size_t)bh * 64 + d) * 512 + (size_t)jt * 64 + j0) = v;
  }
}

// ----------------- fused attention: QK^T+bias -> softmax -> PV -> gate ------
__global__ __launch_bounds__(256) void flash_kernel(
    const _Float16* __restrict__ q16, const _Float16* __restrict__ k16,
    const _Float16* __restrict__ vT, const _Float16* __restrict__ bias16,
    const float* __restrict__ mask, const float* __restrict__ g32,
    _Float16* __restrict__ x16) {
  int bh = blockIdx.y, b = bh >> 4, h = bh & 15;
  int i0 = blockIdx.x * 64;
  __shared__ _Float16 Kc[2][128 * 64];   // K chunks (phase1) / vT chunks (phase2)
  __shared__ _Float16 Bc[2][64 * 128];   // bias chunks
  __shared__ float mk[2][128];
  int t = threadIdx.x, wid = t >> 6, lane = t & 63;
  int lr = lane & 15, hi = lane >> 4;

  // Q as B-operand fragments: lane holds Q[i=wid*16+lr][d = kd*32 + hi*8 + u]
  const _Float16* qrow = q16 + ((size_t)(b * 512) + i0 + wid * 16 + lr) * 1024 + h * 64;
  h8 qf0 = *(const h8*)(qrow + hi * 8);
  h8 qf1 = *(const h8*)(qrow + 32 + hi * 8);

  auto STAGE1 = [&](int c, int buf) {
    int j0 = c * 128;
    const _Float16* kb = k16 + ((size_t)(b * 512) + j0) * 1024 + h * 64;
    const _Float16* bb = bias16 + ((size_t)bh * 512 + i0) * 512 + j0;
#pragma unroll
    for (int p = 0; p < 4; ++p) {
      int q = (wid * 4 + p) * 64 + lane;
      {  // K chunk: 128 rows x 64 d (128 B/row)
        int row = q >> 3, c16 = q & 7;
        int coff = (c16 * 16) ^ ((row & 7) << 4);
        gl_lds16(kb + (size_t)row * 1024 + (coff >> 1),
                 (char*)Kc[buf] + (wid * 4 + p) * 1024);
      }
      {  // bias chunk: 64 rows x 128 j (256 B/row)
        int row = q >> 4, c16 = q & 15;
        int coff = (c16 * 16) ^ ((row & 7) << 4);
        gl_lds16(bb + (size_t)row * 512 + (coff >> 1),
                 (char*)Bc[buf] + (wid * 4 + p) * 1024);
      }
    }
    if (t < 128) mk[buf][t] = (1.0f - mask[b * 512 + j0 + t]) * -1000000.0f;
  };

  // ---- phase 1: S = K q^T + bias + mask (C[j][i]: col=i=lr, row=j=hi*4+r) ---
  f32x4 acc[32];
  STAGE1(0, 0);
  __syncthreads();
#pragma unroll
  for (int c = 0; c < 4; ++c) {
    int buf = c & 1;
    if (c < 3) STAGE1(c + 1, buf ^ 1);
#pragma unroll
    for (int jtl = 0; jtl < 8; ++jtl) {
      int jt = c * 8 + jtl;
      int krow = jtl * 16 + lr;
      h8 kf0 = *(const h8*)((char*)Kc[buf] + krow * 128 + ((hi * 16) ^ ((lr & 7) << 4)));
      h8 kf1 = *(const h8*)((char*)Kc[buf] + krow * 128 + ((64 + hi * 16) ^ ((lr & 7) << 4)));
      int brow = wid * 16 + lr;
      h4 bv = *(const h4*)((char*)Bc[buf] + brow * 256 + ((jtl * 32 + hi * 8) ^ ((lr & 7) << 4)));
      f32x4 mt = *(const f32x4*)&mk[buf][jtl * 16 + hi * 4];
      f32x4 a;
      a[0] = (float)bv[0] + mt[0]; a[1] = (float)bv[1] + mt[1];
      a[2] = (float)bv[2] + mt[2]; a[3] = (float)bv[3] + mt[3];
      a = MFMA16(kf0, qf0, a);
      a = MFMA16(kf1, qf1, a);
      acc[jt] = a;
    }
    __syncthreads();
  }

  // ---- softmax over j for each i=lr (values spread over hi groups) ---------
  float m = -3.4e38f;
#pragma unroll
  for (int jt = 0; jt < 32; ++jt)
    m = fmaxf(m, fmaxf(fmaxf(acc[jt][0], acc[jt][1]), fmaxf(acc[jt][2], acc[jt][3])));
  m = fmaxf(m, __shfl_xor(m, 16, 64));
  m = fmaxf(m, __shfl_xor(m, 32, 64));
  float ssum = 0.f;
#pragma unroll
  for (int jt = 0; jt < 32; ++jt) {
#pragma unroll
    for (int r = 0; r < 4; ++r) {
      float e = __expf(acc[jt][r] - m);
      acc[jt][r] = e;
      ssum += e;
    }
  }
  ssum += __shfl_xor(ssum, 16, 64);
  ssum += __shfl_xor(ssum, 32, 64);
  float inv = 1.0f / ssum;
  u32 pk0[32], pk1[32];
#pragma unroll
  for (int jt = 0; jt < 32; ++jt) {
    pk0[jt] = pkrtz(acc[jt][0] * inv, acc[jt][1] * inv);
    pk1[jt] = pkrtz(acc[jt][2] * inv, acc[jt][3] * inv);
  }

  // ---- phase 2: o = P V (A = P via shfl redistribution, B = vT rows) -------
  auto STAGE2 = [&](int c, int buf) {
    int j0 = c * 128;
    const _Float16* vb = vT + ((size_t)bh * 64) * 512 + j0;
#pragma unroll
    for (int p = 0; p < 4; ++p) {
      int q = (wid * 4 + p) * 64 + lane;
      int row = q >> 4, c16 = q & 15;   // 64 rows x 128 j (256 B/row)
      int coff = (c16 * 16) ^ ((row & 7) << 4);
      gl_lds16(vb + (size_t)row * 512 + (coff >> 1),
               (char*)Kc[buf] + (wid * 4 + p) * 1024);
    }
  };
  f32x4 oacc[4] = {};
  STAGE2(0, 0);
  __syncthreads();
#pragma unroll
  for (int c = 0; c < 4; ++c) {
    int buf = c & 1;
    if (c < 3) STAGE2(c + 1, buf ^ 1);
#pragma unroll
    for (int ktl = 0; ktl < 4; ++ktl) {
      int kt = c * 4 + ktl;
      int la = lr + ((hi & 1) << 5);
      int lb = la + 16;
      u32 a0 = __shfl(pk0[2 * kt], la, 64);
      u32 a1 = __shfl(pk1[2 * kt], la, 64);
      u32 b0 = __shfl(pk0[2 * kt], lb, 64);
      u32 b1 = __shfl(pk1[2 * kt], lb, 64);
      u32 c0 = __shfl(pk0[2 * kt + 1], la, 64);
      u32 c1 = __shfl(pk1[2 * kt + 1], la, 64);
      u32 d0 = __shfl(pk0[2 * kt + 1], lb, 64);
      u32 d1 = __shfl(pk1[2 * kt + 1], lb, 64);
      bool x1 = hi >= 2;
      uint4 au;
      au.x = x1 ? c0 : a0;
      au.y = x1 ? c1 : a1;
      au.z = x1 ? d0 : b0;
      au.w = x1 ? d1 : b1;
      h8 paf = __builtin_bit_cast(h8, au);
#pragma unroll
      for (int nt = 0; nt < 4; ++nt) {
        int vrow = nt * 16 + lr;
        h8 vf = *(const h8*)((char*)Kc[buf] + vrow * 256 + ((ktl * 64 + hi * 16) ^ ((lr & 7) << 4)));
        oacc[nt] = MFMA16(paf, vf, oacc[nt]);
      }
    }
    __syncthreads();
  }

  // ---- epilogue: x = fp16(g * o) -------------------------------------------
  const float* gb = g32 + ((size_t)(b * 512) + i0) * 1024 + h * 64;
  _Float16* xb = x16 + ((size_t)(b * 512) + i0) * 1024 + h * 64;
#pragma unroll
  for (int nt = 0; nt < 4; ++nt)
#pragma unroll
    for (int r = 0; r < 4; ++r) {
      int il = wid * 16 + hi * 4 + r, d = nt * 16 + lr;
      size_t off = (size_t)il * 1024 + d;
      xb[off] = (_Float16)(oacc[nt][r] * gb[off]);
    }
}

// --------------- out = x @ wo, 64^2 tiles, BK=64, gload_lds -----------------
__global__ __launch_bounds__(256) void gemm_o_kernel(
    const _Float16* __restrict__ x16, const _Float16* __restrict__ woT,
    float* __restrict__ out32) {
  int bm = blockIdx.x >> 4, bn = blockIdx.x & 15;
  __shared__ _Float16 As[2][64 * 64];
  __shared__ _Float16 Bs[2][64 * 64];
  int t = threadIdx.x, wid = t >> 6, lane = t & 63;
  int wr = wid >> 1, wc = wid & 1, lr = lane & 15, hi = lane >> 4;
  const _Float16* Ab = x16 + (size_t)(bm * 64) * 1024;
  const _Float16* Bb = woT + (size_t)(bn * 64) * 1024;
  auto STAGE = [&](int kt, int buf) {
    int k0 = kt * 64;
#pragma unroll
    for (int p = 0; p < 2; ++p) {
      int q = (wid * 2 + p) * 64 + lane;   // 0..511 16B-units, 8 per row
      int row = q >> 3, c16 = q & 7;
      int coff = (c16 * 16) ^ ((row & 7) << 4);
      gl_lds16(Ab + (size_t)row * 1024 + k0 + (coff >> 1),
               (char*)As[buf] + (wid * 2 + p) * 1024);
      gl_lds16(Bb + (size_t)row * 1024 + k0 + (coff >> 1),
               (char*)Bs[buf] + (wid * 2 + p) * 1024);
    }
  };
  f32x4 acc[2][2] = {};
  STAGE(0, 0);
  __syncthreads();
  for (int kt = 0; kt < 16; ++kt) {
    int buf = kt & 1;
    if (kt < 15) STAGE(kt + 1, buf ^ 1);
#pragma unroll
    for (int kk = 0; kk < 2; ++kk) {
      h8 af[2], bf[2];
#pragma unroll
      for (int mi = 0; mi < 2; ++mi) {
        int row = wr * 32 + mi * 16 + lr;
        af[mi] = *(const h8*)((char*)As[buf] + row * 128 + ((kk * 64 + hi * 16) ^ ((lr & 7) << 4)));
      }
#pragma unroll
      for (int ni = 0; ni < 2; ++ni) {
        int row = wc * 32 + ni * 16 + lr;
        bf[ni] = *(const h8*)((char*)Bs[buf] + row * 128 + ((kk * 64 + hi * 16) ^ ((lr & 7) << 4)));
      }
#pragma unroll
      for (int mi = 0; mi < 2; ++mi)
#pragma unroll
        for (int ni = 0; ni < 2; ++ni)
          acc[mi][ni] = MFMA16(af[mi], bf[ni], acc[mi][ni]);
    }
    __syncthreads();
  }
#pragma unroll
  for (int mi = 0; mi < 2; ++mi)
#pragma unroll
    for (int ni = 0; ni < 2; ++ni)
#pragma unroll
      for (int r = 0; r < 4; ++r) {
        int row = bm * 64 + wr * 32 + mi * 16 + hi * 4 + r;
        int col = bn * 64 + wc * 32 + ni * 16 + lr;
        out32[(size_t)row * 1024 + col] = acc[mi][ni][r];
      }
}

// ----------------------------------------------------------------------------
extern "C" void kernel_launch(void* const* d_in, const int* in_sizes, int n_in,
                              void* d_out, int out_size, void* d_ws, size_t ws_size,
                              hipStream_t stream) {
  const float* s    = (const float*)d_in[0];
  const float* z    = (const float*)d_in[1];
  const float* mask = (const float*)d_in[2];
  const float* kin  = (const float*)d_in[3];
  const float* wq   = (const float*)d_in[4];
  const float* bq   = (const float*)d_in[5];
  const float* wk   = (const float*)d_in[6];
  const float* wv   = (const float*)d_in[7];
  const float* wg   = (const float*)d_in[8];
  const float* lng  = (const float*)d_in[9];
  const float* lnb  = (const float*)d_in[10];
  const float* wz   = (const float*)d_in[11];
  const float* wo   = (const float*)d_in[12];
  float* out = (float*)d_out;

  char* ws = (char*)d_ws;
  _Float16* s16   = (_Float16*)(ws + OFF_S16);
  _Float16* kin16 = (_Float16*)(ws + OFF_KIN16);
  _Float16* wqT   = (_Float16*)(ws + OFF_WQT);
  _Float16* wkT   = (_Float16*)(ws + OFF_WKT);
  _Float16* wvT   = (_Float16*)(ws + OFF_WVT);
  _Float16* wgT   = (_Float16*)(ws + OFF_WGT);
  _Float16* woT   = (_Float16*)(ws + OFF_WOT);
  _Float16* q16   = (_Float16*)(ws + OFF_Q16);
  _Float16* k16   = (_Float16*)(ws + OFF_K16);
  _Float16* v16   = (_Float16*)(ws + OFF_V16);
  _Float16* vT16  = (_Float16*)(ws + OFF_VT16);
  _Float16* x16   = (_Float16*)(ws + OFF_X16);
  float* g32      = (float*)(ws + OFF_G32);
  _Float16* gwT   = (_Float16*)(ws + OFF_GWT);
  float* Gbw      = (float*)(ws + OFF_GBW);
  _Float16* bias16= (_Float16*)(ws + OFF_BIAS);

  conv_f16_kernel<<<1024, 256, 0, stream>>>(s, kin, s16, kin16);
  convT_f16_kernel<<<dim3(256, 6), 256, 0, stream>>>(wq, wk, wv, wg, wo,
                                                     wqT, wkT, wvT, wgT, woT,
                                                     lng, lnb, wz, gwT, Gbw);
  ln_bias_kernel<<<dim3(8, 512, 2), 256, 0, stream>>>(z, gwT, Gbw, bias16);
  gemm_fused<<<dim3(64, 4), 256, 0, stream>>>(s16, kin16, wqT, wkT, wvT, wgT,
                                              bq, q16, k16, v16, g32);
  transpose_v_kernel<<<dim3(8, 32), 256, 0, stream>>>(v16, vT16);
  flash_kernel<<<dim3(8, 32), 256, 0, stream>>>(q16, k16, vT16, bias16,
                                                mask, g32, x16);
  gemm_o_kernel<<<256, 256, 0, stream>>>(x16, woT, out);
}